// Round 8
// baseline (180.693 us; speedup 1.0000x reference)
//
#include <hip/hip_runtime.h>
#include <math.h>
#include <stdint.h>

// Problem constants
#define BATCH 4
#define SEQ   4096
#define EMB   512
#define PADW  128
#define SPAD  (SEQ + 2*PADW)   // 4352
#define WIN   (3*PADW)         // 384 keys per window

static constexpr float SCALE = 0.04419417382415922f; // 1/sqrt(512)

typedef __attribute__((ext_vector_type(8))) short    s16x8;
typedef __attribute__((ext_vector_type(4))) short    s16x4;
typedef __attribute__((ext_vector_type(4))) float    f32x4;
typedef __attribute__((ext_vector_type(8))) _Float16 f16x8;

__device__ __forceinline__ unsigned short f2h(float x) {  // RNE f32->fp16
  _Float16 h = (_Float16)x;
  return __builtin_bit_cast(unsigned short, h);
}
__device__ __forceinline__ void gload16(const void* g, void* lds) {
  __builtin_amdgcn_global_load_lds(
      (const __attribute__((address_space(1))) uint32_t*)g,
      (__attribute__((address_space(3))) uint32_t*)lds, 16, 0, 0);
}
// LDS tile rows of 128B (8 x 16B slots), slot XOR-swizzled by (row&7).
__device__ __forceinline__ f16x8 frag64(const unsigned short* base, int row, int slot) {
  return *(const f16x8*)((const char*)base + row * 128 + ((slot ^ (row & 7)) << 4));
}

// ---------------------------------------------------------------------------
// x [B,SEQ,512] f32 -> xh [B,SEQ,512] fp16
// ---------------------------------------------------------------------------
__global__ __launch_bounds__(256) void convert_x(const float* __restrict__ x,
                                                 unsigned short* __restrict__ xh) {
  size_t i = ((size_t)blockIdx.x * 256 + threadIdx.x) * 8;
  float4 a = *(const float4*)&x[i];
  float4 c = *(const float4*)&x[i + 4];
  s16x8 o;
  o[0] = (short)f2h(a.x); o[1] = (short)f2h(a.y);
  o[2] = (short)f2h(a.z); o[3] = (short)f2h(a.w);
  o[4] = (short)f2h(c.x); o[5] = (short)f2h(c.y);
  o[6] = (short)f2h(c.z); o[7] = (short)f2h(c.w);
  *(s16x8*)&xh[i] = o;
}

// ---------------------------------------------------------------------------
// W [512 k,512 n] f32 (x3) -> wt [3, 512 n, 512 k] fp16 (transposed)
// ---------------------------------------------------------------------------
__global__ __launch_bounds__(256) void convert_w(const float* __restrict__ Wq,
                                                 const float* __restrict__ Wk,
                                                 const float* __restrict__ Wv,
                                                 unsigned short* __restrict__ wt) {
  const int w = blockIdx.z;
  const float* W = (w == 0) ? Wq : (w == 1) ? Wk : Wv;
  const int kt = blockIdx.x * 64, nt = blockIdx.y * 64;
  __shared__ float T[64][65];
  const int tid = threadIdx.x;
  {
    int r = tid >> 4, c4 = (tid & 15) * 4;
#pragma unroll
    for (int i = 0; i < 4; ++i) {
      float4 v = *(const float4*)&W[(size_t)(kt + r + 16 * i) * EMB + nt + c4];
      T[r + 16 * i][c4 + 0] = v.x;
      T[r + 16 * i][c4 + 1] = v.y;
      T[r + 16 * i][c4 + 2] = v.z;
      T[r + 16 * i][c4 + 3] = v.w;
    }
  }
  __syncthreads();
  {
    int n = tid >> 2, k0 = (tid & 3) * 16;
    __align__(16) unsigned short hb[16];
#pragma unroll
    for (int j = 0; j < 16; ++j) hb[j] = f2h(T[k0 + j][n]);
    size_t base = ((size_t)w * EMB + nt + n) * EMB;
    *(s16x8*)&wt[base + kt + k0]     = *(s16x8*)&hb[0];
    *(s16x8*)&wt[base + kt + k0 + 8] = *(s16x8*)&hb[8];
  }
}

// ---------------------------------------------------------------------------
// Projection GEMM (fp16 MFMA): out = ext(x) @ W + b for q,k,v.
// 128x128 tile, 4 waves, BK=64, global_load_lds(16B), XOR-swizzled LDS.
// w==2 (V) epilogue writes vt TRANSPOSED [B,512 e,SPAD t] via LDS staging.
// Work decode: w FASTEST within each XCD chunk so the 3 blocks sharing an
// A-tile run 8 dispatch-slots apart on the SAME XCD -> A-tile L2/L1-hot.
// ---------------------------------------------------------------------------
__global__ __launch_bounds__(256) void proj_kernel(
    const unsigned short* __restrict__ xh,  // [B,SEQ,512]
    const unsigned short* __restrict__ wt,  // [3,512,512]
    const float* __restrict__ bq, const float* __restrict__ bk, const float* __restrict__ bv,
    unsigned short* __restrict__ qh,   // [B,SPAD,512]
    unsigned short* __restrict__ kh,   // [B,SPAD,512]
    unsigned short* __restrict__ vt)   // [B,512,SPAD] (transposed!)
{
  int linear = blockIdx.x + 34 * (blockIdx.y + 4 * blockIdx.z);
  int swz = (linear & 7) * 204 + (linear >> 3);   // bijective XCD chunking (1632=8*204)
  const int w  = swz % 3;                          // w fastest within chunk
  int rest = swz / 3;                              // 0..543
  const int mt = rest % 34;
  rest /= 34;                                      // 0..15
  const int nt = rest & 3;
  const int b  = rest >> 2;
  const float* bias = (w == 0) ? bq : (w == 1) ? bk : bv;
  const int tid = threadIdx.x, lane = tid & 63, wid = tid >> 6;
  const int t0 = mt * 128, n0 = nt * 128;

  if (mt == 0 || mt == 33) {  // all-pad tiles: Linear(0) = bias
    if (w < 2) {
      unsigned short* om = (w == 0) ? qh : kh;
      for (int i = tid; i < 128 * 128; i += 256) {
        int r = i >> 7, n = i & 127;
        om[((size_t)b * SPAD + t0 + r) * EMB + n0 + n] = f2h(bias[n0 + n]);
      }
    } else {
      for (int i = tid; i < 128 * 128; i += 256) {
        int e = i >> 7, t = i & 127;
        vt[((size_t)b * EMB + n0 + e) * SPAD + t0 + t] = f2h(bias[n0 + e]);
      }
    }
    return;
  }

  __shared__ __align__(16) unsigned short smem[17408];  // 34816 B
  unsigned short* At = smem;          // [128 m][64 k] swz (16 KB)
  unsigned short* Bt = smem + 8192;   // [128 n][64 k] swz (16 KB)

  f32x4 acc[4][4];
#pragma unroll
  for (int i = 0; i < 4; ++i)
#pragma unroll
    for (int j = 0; j < 4; ++j) acc[i][j] = (f32x4){0.f, 0.f, 0.f, 0.f};

  const int xr0 = (mt - 1) * 128;
  const int wm = wid >> 1, wn = wid & 1;

  for (int kt = 0; kt < EMB; kt += 64) {
#pragma unroll
    for (int i = 0; i < 4; ++i) {  // A tile: 1024 16B chunks
      int c = wid * 256 + i * 64 + lane;
      int m = c >> 3, sl = (c & 7) ^ (m & 7);
      gload16(xh + ((size_t)b * SEQ + xr0 + m) * EMB + kt + sl * 8,
              (char*)At + (wid * 256 + i * 64) * 16);
    }
#pragma unroll
    for (int i = 0; i < 4; ++i) {  // B tile
      int c = wid * 256 + i * 64 + lane;
      int n = c >> 3, sl = (c & 7) ^ (n & 7);
      gload16(wt + ((size_t)w * EMB + n0 + n) * EMB + kt + sl * 8,
              (char*)Bt + (wid * 256 + i * 64) * 16);
    }
    __syncthreads();
#pragma unroll
    for (int kk = 0; kk < 2; ++kk) {
      f16x8 af[4], bfr[4];
#pragma unroll
      for (int f = 0; f < 4; ++f)
        af[f] = frag64(At, wm * 64 + f * 16 + (lane & 15), kk * 4 + (lane >> 4));
#pragma unroll
      for (int f = 0; f < 4; ++f)
        bfr[f] = frag64(Bt, wn * 64 + f * 16 + (lane & 15), kk * 4 + (lane >> 4));
#pragma unroll
      for (int fm = 0; fm < 4; ++fm)
#pragma unroll
        for (int fn = 0; fn < 4; ++fn)
          acc[fm][fn] = __builtin_amdgcn_mfma_f32_16x16x32_f16(af[fm], bfr[fn], acc[fm][fn], 0, 0, 0);
    }
    __syncthreads();
  }

  if (w < 2) {  // q/k: direct row-major store
    unsigned short* om = (w == 0) ? qh : kh;
#pragma unroll
    for (int fm = 0; fm < 4; ++fm) {
      int t = t0 + wm * 64 + fm * 16 + ((lane >> 4) << 2);
#pragma unroll
      for (int fn = 0; fn < 4; ++fn) {
        int n = n0 + wn * 64 + fn * 16 + (lane & 15);
        float bsv = bias[n];
#pragma unroll
        for (int r = 0; r < 4; ++r)
          om[((size_t)b * SPAD + t + r) * EMB + n] = f2h(acc[fm][fn][r] + bsv);
      }
    }
  } else {  // V: transpose via LDS, write vt[e][t]
    unsigned short* T = smem;  // [128 e][136 t]
#pragma unroll
    for (int fm = 0; fm < 4; ++fm) {
      int tl = wm * 64 + fm * 16 + ((lane >> 4) << 2);
#pragma unroll
      for (int fn = 0; fn < 4; ++fn) {
        int el = wn * 64 + fn * 16 + (lane & 15);
        float bsv = bias[n0 + el];
        s16x4 pk;
#pragma unroll
        for (int r = 0; r < 4; ++r) pk[r] = (short)f2h(acc[fm][fn][r] + bsv);
        *(s16x4*)&T[el * 136 + tl] = pk;
      }
    }
    __syncthreads();
#pragma unroll
    for (int it = 0; it < 8; ++it) {
      int c = it * 256 + tid;
      int e = c >> 4, t8 = (c & 15) * 8;
      s16x8 vchunk = *(s16x8*)&T[e * 136 + t8];
      *(s16x8*)&vt[((size_t)b * EMB + n0 + e) * SPAD + t0 + t8] = vchunk;
    }
  }
}

// ---------------------------------------------------------------------------
// Banded attention v2: NO K/Q/V LDS staging (zero cross-wave reuse; data is
// L2-resident). MFMA fragments come straight from global as 16B/lane loads.
// LDS holds only P [64 q][384 k] fp16 (shared across waves in PV) + aux.
// 3 barriers total. One wg = 64 queries, 8 waves.
// Phase A: S^T[384,64] = K.Q^T, accs in regs; wave fully out-of-band skips.
// Phase B: mask (direct int4 mask loads) + softmax -> P in LDS.
// Phase C: O = P.V over band-trimmed k in [o, o+320); V frags from vt.
// grid (64, 4) XCD-swizzled (256 = 8*32).
// ---------------------------------------------------------------------------
__global__ __launch_bounds__(512, 4) void attn_kernel(
    const unsigned short* __restrict__ qh,
    const unsigned short* __restrict__ kh,
    const unsigned short* __restrict__ vt,
    const int* __restrict__ mask,
    float* __restrict__ out) {
  int linear = blockIdx.x + 64 * blockIdx.y;
  linear = (linear & 7) * 32 + (linear >> 3);
  const int b  = linear >> 6;
  const int s0 = (linear & 63) * 64;
  const int nb = s0 >> 7, o = s0 & 127;  // o in {0, 64}
  const int t0 = nb * 128;
  const int tid = threadIdx.x, lane = tid & 63, wid = tid >> 6;

  __shared__ __align__(16) char smem[53504];
  unsigned short* P = (unsigned short*)smem;      // [64 q][384 k], 16B-slot XOR (q&7); 48 KB
  float* red  = (float*)(smem + 49152);           // [8][64] cross-wave max
  float* red2 = (float*)(smem + 51200);           // [8][64] cross-wave sum
  float* invl = (float*)(smem + 53248);           // [64]

  const int l15 = lane & 15;
  const int oct = (lane >> 4) << 3;      // k-octet offset within 32-wide step
  const int kr0 = wid * 48;              // wave's k-row base in window

  // ---- phase A: S^T = K.Q^T (direct-from-global fragments) ----
  f32x4 accS[3][4];
#pragma unroll
  for (int i = 0; i < 3; ++i)
#pragma unroll
    for (int j = 0; j < 4; ++j) accS[i][j] = (f32x4){0.f, 0.f, 0.f, 0.f};

  const bool active = (kr0 < o + 320) && (kr0 + 48 > o);  // wave k-range in band?
  if (active) {
    const unsigned short* kp = kh + ((size_t)b * SPAD + t0 + kr0 + l15) * EMB;
    const unsigned short* qp = qh + ((size_t)b * SPAD + PADW + s0 + l15) * EMB;
#pragma unroll 4
    for (int kt = 0; kt < EMB; kt += 32) {
      f16x8 af[3], bfq[4];
#pragma unroll
      for (int f = 0; f < 3; ++f)
        af[f] = *(const f16x8*)&kp[(size_t)f * 16 * EMB + kt + oct];
#pragma unroll
      for (int f = 0; f < 4; ++f)
        bfq[f] = *(const f16x8*)&qp[(size_t)f * 16 * EMB + kt + oct];
#pragma unroll
      for (int fk = 0; fk < 3; ++fk)
#pragma unroll
        for (int fq = 0; fq < 4; ++fq)
          accS[fk][fq] = __builtin_amdgcn_mfma_f32_16x16x32_f16(af[fk], bfq[fq], accS[fk][fq], 0, 0, 0);
    }
  }

  // ---- phase B: mask + softmax ----
  // key-side mask quads, direct from global (pads unmasked = 1)
  float pmv[3][4];
#pragma unroll
  for (int fk = 0; fk < 3; ++fk) {
    int kq = kr0 + fk * 16 + ((lane >> 4) << 2);   // quad-aligned key index
    int tq = t0 + kq - PADW;                        // mask row index
    int4 mv = make_int4(1, 1, 1, 1);
    if (tq >= 0 && tq < SEQ) mv = *(const int4*)&mask[(size_t)b * SEQ + tq];
    pmv[fk][0] = (float)mv.x; pmv[fk][1] = (float)mv.y;
    pmv[fk][2] = (float)mv.z; pmv[fk][3] = (float)mv.w;
  }

  float mx[4] = {-INFINITY, -INFINITY, -INFINITY, -INFINITY};
#pragma unroll
  for (int fk = 0; fk < 3; ++fk)
#pragma unroll
    for (int fq = 0; fq < 4; ++fq)
#pragma unroll
      for (int r = 0; r < 4; ++r) {
        int k = kr0 + fk * 16 + ((lane >> 4) << 2) + r;
        int p = o + fq * 16 + l15;  // query pos in block
        float v;
        if (k < p || k > p + 2 * PADW) v = -INFINITY;                 // band
        else v = (pmv[fk][r] == 0.f) ? -1e9f : accS[fk][fq][r] * SCALE;
        accS[fk][fq][r] = v;
        mx[fq] = fmaxf(mx[fq], v);
      }
#pragma unroll
  for (int fq = 0; fq < 4; ++fq) {
    mx[fq] = fmaxf(mx[fq], __shfl_xor(mx[fq], 16));
    mx[fq] = fmaxf(mx[fq], __shfl_xor(mx[fq], 32));
  }
  if (lane < 16) {
#pragma unroll
    for (int fq = 0; fq < 4; ++fq) red[wid * 64 + fq * 16 + lane] = mx[fq];
  }
  __syncthreads();  // barrier 1
  float M[4];
#pragma unroll
  for (int fq = 0; fq < 4; ++fq) {
    float m = -INFINITY;
#pragma unroll
    for (int ww = 0; ww < 8; ++ww) m = fmaxf(m, red[ww * 64 + fq * 16 + l15]);
    M[fq] = m;
  }
  float sm[4] = {0.f, 0.f, 0.f, 0.f};
#pragma unroll
  for (int fk = 0; fk < 3; ++fk)
#pragma unroll
    for (int fq = 0; fq < 4; ++fq)
#pragma unroll
      for (int r = 0; r < 4; ++r) {
        float pv = __expf(accS[fk][fq][r] - M[fq]);
        accS[fk][fq][r] = pv;
        sm[fq] += pv;
      }
#pragma unroll
  for (int fq = 0; fq < 4; ++fq) {
    sm[fq] += __shfl_xor(sm[fq], 16);
    sm[fq] += __shfl_xor(sm[fq], 32);
  }
  if (lane < 16) {
#pragma unroll
    for (int fq = 0; fq < 4; ++fq) red2[wid * 64 + fq * 16 + lane] = sm[fq];
  }
  __syncthreads();  // barrier 2
  if (wid == 0 && lane < 16) {
#pragma unroll
    for (int fq = 0; fq < 4; ++fq) {
      float s = 0.f;
#pragma unroll
      for (int ww = 0; ww < 8; ++ww) s += red2[ww * 64 + fq * 16 + lane];
      invl[fq * 16 + lane] = 1.f / s;
    }
  }
  // write P (fp16, unnormalized): [64 q][384 k], 16B-slot XOR (q&7)
#pragma unroll
  for (int fk = 0; fk < 3; ++fk)
#pragma unroll
    for (int fq = 0; fq < 4; ++fq) {
      int k0 = kr0 + fk * 16 + ((lane >> 4) << 2);
      int q = fq * 16 + l15;
      s16x4 pk;
      pk[0] = (short)f2h(accS[fk][fq][0]);
      pk[1] = (short)f2h(accS[fk][fq][1]);
      pk[2] = (short)f2h(accS[fk][fq][2]);
      pk[3] = (short)f2h(accS[fk][fq][3]);
      int sl = k0 >> 3;
      *(s16x4*)((char*)P + q * 768 + ((sl ^ (q & 7)) << 4) + ((k0 & 7) << 1)) = pk;
    }
  __syncthreads();  // barrier 3

  // ---- phase C: O = P.V over k in [o, o+320) (band union of 64 queries) ----
  f32x4 accO[4][4];
#pragma unroll
  for (int i = 0; i < 4; ++i)
#pragma unroll
    for (int j = 0; j < 4; ++j) accO[i][j] = (f32x4){0.f, 0.f, 0.f, 0.f};

  const unsigned short* vp = vt + ((size_t)b * EMB + wid * 64 + l15) * SPAD + t0;
#pragma unroll 2
  for (int kb = o; kb < o + 320; kb += 32) {
    f16x8 pa[4], vb[4];
#pragma unroll
    for (int fq = 0; fq < 4; ++fq) {
      int q = fq * 16 + l15;
      int sl = (kb >> 3) + (lane >> 4);
      pa[fq] = *(const f16x8*)((const char*)P + q * 768 + ((sl ^ (q & 7)) << 4));
    }
#pragma unroll
    for (int fe = 0; fe < 4; ++fe)
      vb[fe] = *(const f16x8*)&vp[(size_t)fe * 16 * SPAD + kb + oct];
#pragma unroll
    for (int fq = 0; fq < 4; ++fq)
#pragma unroll
      for (int fe = 0; fe < 4; ++fe)
        accO[fq][fe] = __builtin_amdgcn_mfma_f32_16x16x32_f16(pa[fq], vb[fe], accO[fq][fe], 0, 0, 0);
  }

  // epilogue: normalize by 1/l, zero masked queries (direct int4 mask loads)
#pragma unroll
  for (int fq = 0; fq < 4; ++fq) {
    int qq = fq * 16 + ((lane >> 4) << 2);
    int4 mq4 = *(const int4*)&mask[(size_t)b * SEQ + s0 + qq];
    int mqa[4] = {mq4.x, mq4.y, mq4.z, mq4.w};
#pragma unroll
    for (int r = 0; r < 4; ++r) {
      int q = qq + r;
      float sc = invl[q] * ((mqa[r] != 0) ? 1.f : 0.f);
#pragma unroll
      for (int fe = 0; fe < 4; ++fe) {
        int e = wid * 64 + fe * 16 + l15;
        out[((size_t)b * SEQ + s0 + q) * EMB + e] = accO[fq][fe][r] * sc;
      }
    }
  }
}

// ---------------------------------------------------------------------------
extern "C" void kernel_launch(void* const* d_in, const int* in_sizes, int n_in,
                              void* d_out, int out_size, void* d_ws, size_t ws_size,
                              hipStream_t stream) {
  const float* x  = (const float*)d_in[0];
  const int* mask = (const int*)d_in[1];
  const float* Wq = (const float*)d_in[2];
  const float* bq = (const float*)d_in[3];
  const float* Wk = (const float*)d_in[4];
  const float* bk = (const float*)d_in[5];
  const float* Wv = (const float*)d_in[6];
  const float* bv = (const float*)d_in[7];
  float* out = (float*)d_out;

  char* ws = (char*)d_ws;
  unsigned short* xh = (unsigned short*)ws;               // [B,SEQ,512]
  unsigned short* wt = (unsigned short*)(ws + 16777216);  // [3,512,512]
  unsigned short* qh = (unsigned short*)(ws + 18350080);  // [B,SPAD,512]
  unsigned short* kh = (unsigned short*)(ws + 36175872);  // [B,SPAD,512]
  unsigned short* vt = (unsigned short*)(ws + 54001664);  // [B,512,SPAD]

  convert_x<<<dim3(4096), 256, 0, stream>>>(x, xh);
  convert_w<<<dim3(8, 8, 3), 256, 0, stream>>>(Wq, Wk, Wv, wt);
  proj_kernel<<<dim3(34, 4, 12), 256, 0, stream>>>(xh, wt, bq, bk, bv, qh, kh, vt);
  attn_kernel<<<dim3(SEQ / 64, BATCH), 512, 0, stream>>>(qh, kh, vt, mask, out);
}

// Round 10
// 174.039 us; speedup vs baseline: 1.0382x; 1.0382x over previous
//
#include <hip/hip_runtime.h>
#include <math.h>
#include <stdint.h>

// Problem constants
#define BATCH 4
#define SEQ   4096
#define EMB   512
#define PADW  128
#define SPAD  (SEQ + 2*PADW)   // 4352
#define WIN   (3*PADW)         // 384 keys per window

static constexpr float SCALE = 0.04419417382415922f; // 1/sqrt(512)

typedef __attribute__((ext_vector_type(8))) short    s16x8;
typedef __attribute__((ext_vector_type(4))) short    s16x4;
typedef __attribute__((ext_vector_type(4))) float    f32x4;
typedef __attribute__((ext_vector_type(8))) _Float16 f16x8;

// zero source row for pad-row global_load_lds redirection (module-load zeroed)
__device__ __align__(16) unsigned short ZROW[8];

__device__ __forceinline__ unsigned short f2h(float x) {  // RNE f32->fp16
  _Float16 h = (_Float16)x;
  return __builtin_bit_cast(unsigned short, h);
}
__device__ __forceinline__ void gload16(const void* g, void* lds) {
  __builtin_amdgcn_global_load_lds(
      (const __attribute__((address_space(1))) uint32_t*)g,
      (__attribute__((address_space(3))) uint32_t*)lds, 16, 0, 0);
}
// LDS tile rows of 128B (8 x 16B slots), slot XOR-swizzled by (row&7).
__device__ __forceinline__ f16x8 frag64(const unsigned short* base, int row, int slot) {
  return *(const f16x8*)((const char*)base + row * 128 + ((slot ^ (row & 7)) << 4));
}

// ---------------------------------------------------------------------------
// x [B,SEQ,512] f32 -> xh [B,SEQ,512] fp16
// ---------------------------------------------------------------------------
__global__ __launch_bounds__(256) void convert_x(const float* __restrict__ x,
                                                 unsigned short* __restrict__ xh) {
  size_t i = ((size_t)blockIdx.x * 256 + threadIdx.x) * 8;
  float4 a = *(const float4*)&x[i];
  float4 c = *(const float4*)&x[i + 4];
  s16x8 o;
  o[0] = (short)f2h(a.x); o[1] = (short)f2h(a.y);
  o[2] = (short)f2h(a.z); o[3] = (short)f2h(a.w);
  o[4] = (short)f2h(c.x); o[5] = (short)f2h(c.y);
  o[6] = (short)f2h(c.z); o[7] = (short)f2h(c.w);
  *(s16x8*)&xh[i] = o;
}

// ---------------------------------------------------------------------------
// W [512 k,512 n] f32 (x3) -> wt [3, 512 n, 512 k] fp16 (transposed)
// ---------------------------------------------------------------------------
__global__ __launch_bounds__(256) void convert_w(const float* __restrict__ Wq,
                                                 const float* __restrict__ Wk,
                                                 const float* __restrict__ Wv,
                                                 unsigned short* __restrict__ wt) {
  const int w = blockIdx.z;
  const float* W = (w == 0) ? Wq : (w == 1) ? Wk : Wv;
  const int kt = blockIdx.x * 64, nt = blockIdx.y * 64;
  __shared__ float T[64][65];
  const int tid = threadIdx.x;
  {
    int r = tid >> 4, c4 = (tid & 15) * 4;
#pragma unroll
    for (int i = 0; i < 4; ++i) {
      float4 v = *(const float4*)&W[(size_t)(kt + r + 16 * i) * EMB + nt + c4];
      T[r + 16 * i][c4 + 0] = v.x;
      T[r + 16 * i][c4 + 1] = v.y;
      T[r + 16 * i][c4 + 2] = v.z;
      T[r + 16 * i][c4 + 3] = v.w;
    }
  }
  __syncthreads();
  {
    int n = tid >> 2, k0 = (tid & 3) * 16;
    __align__(16) unsigned short hb[16];
#pragma unroll
    for (int j = 0; j < 16; ++j) hb[j] = f2h(T[k0 + j][n]);
    size_t base = ((size_t)w * EMB + nt + n) * EMB;
    *(s16x8*)&wt[base + kt + k0]     = *(s16x8*)&hb[0];
    *(s16x8*)&wt[base + kt + k0 + 8] = *(s16x8*)&hb[8];
  }
}

// ---------------------------------------------------------------------------
// Projection GEMM v2 (fp16 MFMA): 256x128 tile, 8 waves (512 thr), BK=64.
// Halves block count vs 128x128 (816 blocks = 3.2 rounds/CU) to cut the
// round-quantization stall that dominated at 50 us. Pad rows handled by
// redirecting per-lane global_load_lds source to ZROW (no aligned-pad tiles).
// w==2 (V) epilogue transposes in TWO 128-col halves (fits 48KB LDS).
// Decode: w fastest within XCD chunk (A-panel L2 reuse, proven r8).
// grid (17, 4, 12) -> 816 = 8*102 bijective XCD swizzle.
// ---------------------------------------------------------------------------
__global__ __launch_bounds__(512) void proj_kernel(
    const unsigned short* __restrict__ xh,  // [B,SEQ,512]
    const unsigned short* __restrict__ wt,  // [3,512,512]
    const float* __restrict__ bq, const float* __restrict__ bk, const float* __restrict__ bv,
    unsigned short* __restrict__ qh,   // [B,SPAD,512]
    unsigned short* __restrict__ kh,   // [B,SPAD,512]
    unsigned short* __restrict__ vt)   // [B,512,SPAD] (transposed!)
{
  int linear = blockIdx.x + 17 * (blockIdx.y + 4 * blockIdx.z);
  int swz = (linear & 7) * 102 + (linear >> 3);   // bijective (816 = 8*102)
  const int w = swz % 3;                           // w fastest (102 % 3 == 0)
  int rr = swz / 3;                                // 0..271
  const int mt = rr % 17;
  int rest = rr / 17;                              // 0..15
  const int nt = rest & 3;
  const int b  = rest >> 2;                        // 0..3
  const float* bias = (w == 0) ? bq : (w == 1) ? bk : bv;
  const int tid = threadIdx.x, lane = tid & 63, wid = tid >> 6;
  const int t0 = mt * 256, n0 = nt * 128;
  const int xr0 = t0 - PADW;

  __shared__ __align__(16) unsigned short smem[24576];  // 48 KB
  unsigned short* At = smem;           // [256 m][64 k] swz (32 KB)
  unsigned short* Bt = smem + 16384;   // [128 n][64 k] swz (16 KB)

  f32x4 acc[4][4];
#pragma unroll
  for (int i = 0; i < 4; ++i)
#pragma unroll
    for (int j = 0; j < 4; ++j) acc[i][j] = (f32x4){0.f, 0.f, 0.f, 0.f};

  const int wm = wid >> 1, wn = wid & 1;   // wm 0..3 (64 m-rows), wn 0..1 (64 n-cols)
  const int l15 = lane & 15;

  for (int kt = 0; kt < EMB; kt += 64) {
#pragma unroll
    for (int i = 0; i < 4; ++i) {  // A tile: 2048 16B chunks, pad rows -> ZROW
      int c = i * 512 + tid;
      int m = c >> 3, sl = (c & 7) ^ (m & 7);
      int xr = xr0 + m;
      const unsigned short* src = (xr >= 0 && xr < SEQ)
          ? xh + ((size_t)b * SEQ + xr) * EMB + kt + sl * 8 : ZROW;
      gload16(src, (char*)At + c * 16);
    }
#pragma unroll
    for (int i = 0; i < 2; ++i) {  // B tile: 1024 chunks
      int c = i * 512 + tid;
      int n = c >> 3, sl = (c & 7) ^ (n & 7);
      gload16(wt + ((size_t)w * EMB + n0 + n) * EMB + kt + sl * 8,
              (char*)Bt + c * 16);
    }
    __syncthreads();
#pragma unroll
    for (int kk = 0; kk < 2; ++kk) {
      f16x8 af[4], bfr[4];
#pragma unroll
      for (int f = 0; f < 4; ++f)
        af[f] = frag64(At, wm * 64 + f * 16 + l15, kk * 4 + (lane >> 4));
#pragma unroll
      for (int f = 0; f < 4; ++f)
        bfr[f] = frag64(Bt, wn * 64 + f * 16 + l15, kk * 4 + (lane >> 4));
#pragma unroll
      for (int fm = 0; fm < 4; ++fm)
#pragma unroll
        for (int fn = 0; fn < 4; ++fn)
          acc[fm][fn] = __builtin_amdgcn_mfma_f32_16x16x32_f16(af[fm], bfr[fn], acc[fm][fn], 0, 0, 0);
    }
    __syncthreads();
  }

  if (w < 2) {  // q/k: direct row-major store
    unsigned short* om = (w == 0) ? qh : kh;
#pragma unroll
    for (int fm = 0; fm < 4; ++fm) {
      int t = t0 + wm * 64 + fm * 16 + ((lane >> 4) << 2);
#pragma unroll
      for (int fn = 0; fn < 4; ++fn) {
        int n = n0 + wn * 64 + fn * 16 + l15;
        float bsv = bias[n];
#pragma unroll
        for (int r = 0; r < 4; ++r)
          om[((size_t)b * SPAD + t + r) * EMB + n] = f2h(acc[fm][fn][r] + bsv);
      }
    }
  } else {  // V: transpose via LDS in two 128-row halves, write vt[e][t]
    unsigned short* T = smem;  // [128 e][136 t] = 34.8 KB (reuses At/Bt)
#pragma unroll
    for (int h = 0; h < 2; ++h) {
      if ((wm >> 1) == h) {    // waves owning t-rows [h*128, h*128+128)
#pragma unroll
        for (int fm = 0; fm < 4; ++fm) {
          int tl = (wm & 1) * 64 + fm * 16 + ((lane >> 4) << 2);  // local t in [0,128)
#pragma unroll
          for (int fn = 0; fn < 4; ++fn) {
            int el = wn * 64 + fn * 16 + l15;
            float bsv = bias[n0 + el];
            s16x4 pk;
#pragma unroll
            for (int r = 0; r < 4; ++r) pk[r] = (short)f2h(acc[fm][fn][r] + bsv);
            *(s16x4*)&T[el * 136 + tl] = pk;
          }
        }
      }
      __syncthreads();
#pragma unroll
      for (int it = 0; it < 4; ++it) {  // 2048 16B chunks out
        int c = it * 512 + tid;
        int e = c >> 4, t8 = (c & 15) * 8;
        s16x8 vchunk = *(s16x8*)&T[e * 136 + t8];
        *(s16x8*)&vt[((size_t)b * EMB + n0 + e) * SPAD + t0 + h * 128 + t8] = vchunk;
      }
      __syncthreads();
    }
  }
}

// ---------------------------------------------------------------------------
// Banded attention v2 (unchanged from r8): no K/Q/V LDS staging; fragments
// direct from global; LDS only P + softmax aux; 3 barriers.
// grid (64, 4) XCD-swizzled (256 = 8*32).
// ---------------------------------------------------------------------------
__global__ __launch_bounds__(512, 4) void attn_kernel(
    const unsigned short* __restrict__ qh,
    const unsigned short* __restrict__ kh,
    const unsigned short* __restrict__ vt,
    const int* __restrict__ mask,
    float* __restrict__ out) {
  int linear = blockIdx.x + 64 * blockIdx.y;
  linear = (linear & 7) * 32 + (linear >> 3);
  const int b  = linear >> 6;
  const int s0 = (linear & 63) * 64;
  const int nb = s0 >> 7, o = s0 & 127;  // o in {0, 64}
  const int t0 = nb * 128;
  const int tid = threadIdx.x, lane = tid & 63, wid = tid >> 6;

  __shared__ __align__(16) char smem[53504];
  unsigned short* P = (unsigned short*)smem;      // [64 q][384 k], 16B-slot XOR (q&7); 48 KB
  float* red  = (float*)(smem + 49152);           // [8][64] cross-wave max
  float* red2 = (float*)(smem + 51200);           // [8][64] cross-wave sum
  float* invl = (float*)(smem + 53248);           // [64]

  const int l15 = lane & 15;
  const int oct = (lane >> 4) << 3;      // k-octet offset within 32-wide step
  const int kr0 = wid * 48;              // wave's k-row base in window

  // ---- phase A: S^T = K.Q^T (direct-from-global fragments) ----
  f32x4 accS[3][4];
#pragma unroll
  for (int i = 0; i < 3; ++i)
#pragma unroll
    for (int j = 0; j < 4; ++j) accS[i][j] = (f32x4){0.f, 0.f, 0.f, 0.f};

  const bool active = (kr0 < o + 320) && (kr0 + 48 > o);  // wave k-range in band?
  if (active) {
    const unsigned short* kp = kh + ((size_t)b * SPAD + t0 + kr0 + l15) * EMB;
    const unsigned short* qp = qh + ((size_t)b * SPAD + PADW + s0 + l15) * EMB;
#pragma unroll 4
    for (int kt = 0; kt < EMB; kt += 32) {
      f16x8 af[3], bfq[4];
#pragma unroll
      for (int f = 0; f < 3; ++f)
        af[f] = *(const f16x8*)&kp[(size_t)f * 16 * EMB + kt + oct];
#pragma unroll
      for (int f = 0; f < 4; ++f)
        bfq[f] = *(const f16x8*)&qp[(size_t)f * 16 * EMB + kt + oct];
#pragma unroll
      for (int fk = 0; fk < 3; ++fk)
#pragma unroll
        for (int fq = 0; fq < 4; ++fq)
          accS[fk][fq] = __builtin_amdgcn_mfma_f32_16x16x32_f16(af[fk], bfq[fq], accS[fk][fq], 0, 0, 0);
    }
  }

  // ---- phase B: mask + softmax ----
  float pmv[3][4];
#pragma unroll
  for (int fk = 0; fk < 3; ++fk) {
    int kq = kr0 + fk * 16 + ((lane >> 4) << 2);   // quad-aligned key index
    int tq = t0 + kq - PADW;                        // mask row index
    int4 mv = make_int4(1, 1, 1, 1);
    if (tq >= 0 && tq < SEQ) mv = *(const int4*)&mask[(size_t)b * SEQ + tq];
    pmv[fk][0] = (float)mv.x; pmv[fk][1] = (float)mv.y;
    pmv[fk][2] = (float)mv.z; pmv[fk][3] = (float)mv.w;
  }

  float mx[4] = {-INFINITY, -INFINITY, -INFINITY, -INFINITY};
#pragma unroll
  for (int fk = 0; fk < 3; ++fk)
#pragma unroll
    for (int fq = 0; fq < 4; ++fq)
#pragma unroll
      for (int r = 0; r < 4; ++r) {
        int k = kr0 + fk * 16 + ((lane >> 4) << 2) + r;
        int p = o + fq * 16 + l15;  // query pos in block
        float v;
        if (k < p || k > p + 2 * PADW) v = -INFINITY;                 // band
        else v = (pmv[fk][r] == 0.f) ? -1e9f : accS[fk][fq][r] * SCALE;
        accS[fk][fq][r] = v;
        mx[fq] = fmaxf(mx[fq], v);
      }
#pragma unroll
  for (int fq = 0; fq < 4; ++fq) {
    mx[fq] = fmaxf(mx[fq], __shfl_xor(mx[fq], 16));
    mx[fq] = fmaxf(mx[fq], __shfl_xor(mx[fq], 32));
  }
  if (lane < 16) {
#pragma unroll
    for (int fq = 0; fq < 4; ++fq) red[wid * 64 + fq * 16 + lane] = mx[fq];
  }
  __syncthreads();  // barrier 1
  float M[4];
#pragma unroll
  for (int fq = 0; fq < 4; ++fq) {
    float m = -INFINITY;
#pragma unroll
    for (int ww = 0; ww < 8; ++ww) m = fmaxf(m, red[ww * 64 + fq * 16 + l15]);
    M[fq] = m;
  }
  float sm[4] = {0.f, 0.f, 0.f, 0.f};
#pragma unroll
  for (int fk = 0; fk < 3; ++fk)
#pragma unroll
    for (int fq = 0; fq < 4; ++fq)
#pragma unroll
      for (int r = 0; r < 4; ++r) {
        float pv = __expf(accS[fk][fq][r] - M[fq]);
        accS[fk][fq][r] = pv;
        sm[fq] += pv;
      }
#pragma unroll
  for (int fq = 0; fq < 4; ++fq) {
    sm[fq] += __shfl_xor(sm[fq], 16);
    sm[fq] += __shfl_xor(sm[fq], 32);
  }
  if (lane < 16) {
#pragma unroll
    for (int fq = 0; fq < 4; ++fq) red2[wid * 64 + fq * 16 + lane] = sm[fq];
  }
  __syncthreads();  // barrier 2
  if (wid == 0 && lane < 16) {
#pragma unroll
    for (int fq = 0; fq < 4; ++fq) {
      float s = 0.f;
#pragma unroll
      for (int ww = 0; ww < 8; ++ww) s += red2[ww * 64 + fq * 16 + lane];
      invl[fq * 16 + lane] = 1.f / s;
    }
  }
  // write P (fp16, unnormalized): [64 q][384 k], 16B-slot XOR (q&7)
#pragma unroll
  for (int fk = 0; fk < 3; ++fk)
#pragma unroll
    for (int fq = 0; fq < 4; ++fq) {
      int k0 = kr0 + fk * 16 + ((lane >> 4) << 2);
      int q = fq * 16 + l15;
      s16x4 pk;
      pk[0] = (short)f2h(accS[fk][fq][0]);
      pk[1] = (short)f2h(accS[fk][fq][1]);
      pk[2] = (short)f2h(accS[fk][fq][2]);
      pk[3] = (short)f2h(accS[fk][fq][3]);
      int sl = k0 >> 3;
      *(s16x4*)((char*)P + q * 768 + ((sl ^ (q & 7)) << 4) + ((k0 & 7) << 1)) = pk;
    }
  __syncthreads();  // barrier 3

  // ---- phase C: O = P.V over k in [o, o+320) ----
  f32x4 accO[4][4];
#pragma unroll
  for (int i = 0; i < 4; ++i)
#pragma unroll
    for (int j = 0; j < 4; ++j) accO[i][j] = (f32x4){0.f, 0.f, 0.f, 0.f};

  const unsigned short* vp = vt + ((size_t)b * EMB + wid * 64 + l15) * SPAD + t0;
#pragma unroll 2
  for (int kb = o; kb < o + 320; kb += 32) {
    f16x8 pa[4], vb[4];
#pragma unroll
    for (int fq = 0; fq < 4; ++fq) {
      int q = fq * 16 + l15;
      int sl = (kb >> 3) + (lane >> 4);
      pa[fq] = *(const f16x8*)((const char*)P + q * 768 + ((sl ^ (q & 7)) << 4));
    }
#pragma unroll
    for (int fe = 0; fe < 4; ++fe)
      vb[fe] = *(const f16x8*)&vp[(size_t)fe * 16 * SPAD + kb + oct];
#pragma unroll
    for (int fq = 0; fq < 4; ++fq)
#pragma unroll
      for (int fe = 0; fe < 4; ++fe)
        accO[fq][fe] = __builtin_amdgcn_mfma_f32_16x16x32_f16(pa[fq], vb[fe], accO[fq][fe], 0, 0, 0);
  }

  // epilogue: normalize by 1/l, zero masked queries
#pragma unroll
  for (int fq = 0; fq < 4; ++fq) {
    int qq = fq * 16 + ((lane >> 4) << 2);
    int4 mq4 = *(const int4*)&mask[(size_t)b * SEQ + s0 + qq];
    int mqa[4] = {mq4.x, mq4.y, mq4.z, mq4.w};
#pragma unroll
    for (int r = 0; r < 4; ++r) {
      int q = qq + r;
      float sc = invl[q] * ((mqa[r] != 0) ? 1.f : 0.f);
#pragma unroll
      for (int fe = 0; fe < 4; ++fe) {
        int e = wid * 64 + fe * 16 + l15;
        out[((size_t)b * SEQ + s0 + q) * EMB + e] = accO[fq][fe][r] * sc;
      }
    }
  }
}

// ---------------------------------------------------------------------------
extern "C" void kernel_launch(void* const* d_in, const int* in_sizes, int n_in,
                              void* d_out, int out_size, void* d_ws, size_t ws_size,
                              hipStream_t stream) {
  const float* x  = (const float*)d_in[0];
  const int* mask = (const int*)d_in[1];
  const float* Wq = (const float*)d_in[2];
  const float* bq = (const float*)d_in[3];
  const float* Wk = (const float*)d_in[4];
  const float* bk = (const float*)d_in[5];
  const float* Wv = (const float*)d_in[6];
  const float* bv = (const float*)d_in[7];
  float* out = (float*)d_out;

  char* ws = (char*)d_ws;
  unsigned short* xh = (unsigned short*)ws;               // [B,SEQ,512]
  unsigned short* wt = (unsigned short*)(ws + 16777216);  // [3,512,512]
  unsigned short* qh = (unsigned short*)(ws + 18350080);  // [B,SPAD,512]
  unsigned short* kh = (unsigned short*)(ws + 36175872);  // [B,SPAD,512]
  unsigned short* vt = (unsigned short*)(ws + 54001664);  // [B,512,SPAD]

  convert_x<<<dim3(4096), 256, 0, stream>>>(x, xh);
  convert_w<<<dim3(8, 8, 3), 256, 0, stream>>>(Wq, Wk, Wv, wt);
  proj_kernel<<<dim3(17, 4, 12), 512, 0, stream>>>(xh, wt, bq, bk, bv, qh, kh, vt);
  attn_kernel<<<dim3(SEQ / 64, BATCH), 512, 0, stream>>>(qh, kh, vt, mask, out);
}